// Round 17
// baseline (159.790 us; speedup 1.0000x reference)
//
#include <hip/hip_runtime.h>

#define NN 100000
#define EE 1600000
#define FDIM 224
#define OUTC 112

// LDS byte offsets (80KB total -> 2 blocks/CU)
#define SPO 0        // scalars [64][128] bf16 (16KB); after A: x_eq [64][96] bf16
#define HP0 16384    // H col-group ping (16KB)
#define HP1 32768    // H col-group pong (16KB)
#define RNG 49152    // weight ring: 2 x 8KB
#define WMO 65536    // Wm quarter (single buffer, 16KB)
#define LDSZ 81920

typedef __attribute__((ext_vector_type(8))) short bf16x8;
typedef __attribute__((ext_vector_type(8))) unsigned short u16x8;
typedef __attribute__((ext_vector_type(4))) float f32x4;
typedef __attribute__((ext_vector_type(4))) unsigned int u32x4;
typedef __attribute__((ext_vector_type(4))) int i32x4;

__device__ __forceinline__ unsigned short f2bf(float f) {
  unsigned u = __builtin_bit_cast(unsigned, f);
  u = (u + 0x7FFFu + ((u >> 16) & 1u)) >> 16;   // RNE
  return (unsigned short)u;
}
__device__ __forceinline__ float bf2f(unsigned short h) {
  return __builtin_bit_cast(float, (unsigned)h << 16);
}
__device__ __forceinline__ unsigned cvtpk(float lo, float hi) {
  unsigned d;
  asm("v_cvt_pk_bf16_f32 %0, %1, %2" : "=v"(d) : "v"(lo), "v"(hi));
  return d;
}
__device__ __forceinline__ float fast_exp2(float t) {
  float e; asm("v_exp_f32 %0, %1" : "=v"(e) : "v"(t)); return e;
}
__device__ __forceinline__ float fast_rcp(float x) {
  float r; asm("v_rcp_f32 %0, %1" : "=v"(r) : "v"(x)); return r;
}
__device__ __forceinline__ float silu_rs(float a) {     // silu(a / sqrt(128))
  float v = a * 0.08838834764831845f;
  float e = fast_exp2(v * -1.442695041f);
  return v * fast_rcp(1.f + e);
}
__device__ __forceinline__ void gl_lds16(const unsigned short* g, char* l) {
  __builtin_amdgcn_global_load_lds(
      (const __attribute__((address_space(1))) unsigned int*)g,
      (__attribute__((address_space(3))) unsigned int*)l, 16, 0, 0);
}

#define WAITV(n) do { asm volatile("s_waitcnt vmcnt(" #n ")" ::: "memory"); \
                      __builtin_amdgcn_sched_barrier(0); } while (0)
#define LGKM0() asm volatile("s_waitcnt lgkmcnt(0)" ::: "memory")
#define LGKM_BAR() do { asm volatile("s_waitcnt lgkmcnt(0)" ::: "memory"); \
                        __builtin_amdgcn_s_barrier(); } while (0)
#define KEEP(x) asm volatile("" :: "v"(x))
#define MFMA(A, B, C) __builtin_amdgcn_mfma_f32_16x16x32_bf16((A), (B), (C), 0, 0, 0)

// ---- prep kernels (proven) ----------------------------------------------
__global__ void k_zero(unsigned int* p, int n) {
  int i = blockIdx.x * 256 + threadIdx.x;
  if (i < n) p[i] = 0u;
}

__global__ void k_scatter(const int* __restrict__ ei, unsigned char* __restrict__ act) {
  int e4 = blockIdx.x * 256 + threadIdx.x;
  if (e4 < EE / 4) {
    i32x4 v = *(const i32x4*)(ei + e4 * 4);
#pragma unroll
    for (int j = 0; j < 4; ++j) {
      int n = v[j];
      if (!act[n]) act[n] = 1;
    }
  }
}

__global__ void k_wprep(const float* __restrict__ invW1, const float* __restrict__ invW2,
                        const float* __restrict__ wembW1, const float* __restrict__ wembW2,
                        unsigned short* __restrict__ W1s, unsigned short* __restrict__ W2w,
                        unsigned short* __restrict__ W2i) {
  int i = blockIdx.x * 256 + threadIdx.x;
  if (i < 65536) {
    int c = i >> 12, j = i & 4095;
    int r128 = j >> 5, slot = (j >> 3) & 3, e = j & 7;
    int gg = slot ^ (r128 & 3);
    int n = (c >> 2) * 128 + r128;
    int k = (c & 3) * 32 + gg * 8 + e;
    float v = (n < 256) ? invW1[k * 256 + n] : wembW1[k * 256 + (n - 256)];
    W1s[i] = f2bf(v);
  } else if (i < 196608) {
    int t = i - 65536;
    int c = t >> 12, j = t & 4095;
    int r128 = j >> 5, slot = (j >> 3) & 3, e = j & 7;
    int gg = slot ^ (r128 & 3);
    int n = (c >> 3) * 128 + r128;
    int k = (c & 7) * 32 + gg * 8 + e;
    W2w[t] = f2bf(wembW2[k * 512 + n]);
  } else if (i < 212992) {
    int t = i - 196608;
    int n = t >> 8, k = t & 255;
    W2i[t] = f2bf(invW2[k * 64 + n]);
  }
}

// ---- fused main kernel: BM=64, 48-step counted-vmcnt engine -------------
// 64 nodes/block, 512 thr (8 waves), LDS 80KB -> 2 blocks/CU. Grid 1563.
// Wm single-buffer safety (r16 bugfix): LGKM_BAR *before* each quarter
// write (all waves' prior-quarter reads complete) + LGKM_BAR after (publish).
__global__ __launch_bounds__(512, 4) void k_main(
    const float* __restrict__ feats,
    const unsigned short* __restrict__ Wall,   // W1s(0..15) ++ W2w(16..47)
    const unsigned short* __restrict__ W2i,
    const unsigned char* __restrict__ act,
    float* __restrict__ out) {
  __shared__ char smem[LDSZ];
  const int tid = threadIdx.x;
  const int lane = tid & 63;
  const int wv = tid >> 6;
  const int o = lane & 15;
  const int g = lane >> 4;
  const int base = blockIdx.x * 64;
  const int rw = wv & 1, cw = wv >> 1;        // inv tile roles (64x64)
  const int nloc = tid >> 3, q = tid & 7;     // phase-C roles (8 thr/node)

  const float inv16 = 0.0625f;
  const float rs32  = 0.17677669529663687f;

  // ---- prologue: all compiler loads issued, converted, drained ---------
  const int srow = tid >> 3, sq = tid & 7;
  int gnode = base + srow; if (gnode > NN - 1) gnode = NN - 1;
  const float* sp = feats + (size_t)gnode * FDIM + sq * 16;
  f32x4 s0 = *(const f32x4*)sp;
  f32x4 s1 = *(const f32x4*)(sp + 4);
  f32x4 s2 = *(const f32x4*)(sp + 8);
  f32x4 s3 = *(const f32x4*)(sp + 12);
  const float* xp = feats + (size_t)gnode * FDIM + 128 + sq * 12;
  f32x4 x0 = *(const f32x4*)xp;
  f32x4 x1 = *(const f32x4*)(xp + 4);
  f32x4 x2 = *(const f32x4*)(xp + 8);

  bf16x8 b2f[8];
#pragma unroll
  for (int kk = 0; kk < 8; ++kk)
    b2f[kk] = *(const bf16x8*)(W2i + (cw * 16 + o) * 256 + kk * 32 + g * 8);
  float invm[8];
#pragma unroll
  for (int rt = 0; rt < 2; ++rt)
#pragma unroll
    for (int r = 0; r < 4; ++r) {
      int node = base + rw * 32 + rt * 16 + g * 4 + r;
      invm[rt * 4 + r] = (node < NN && act[node < NN ? node : 0]) ? inv16 : 0.f;
    }
  const float sCv = (base + nloc < NN && act[base + nloc < NN ? base + nloc : 0]) ? rs32 : 0.f;

  // scalars -> SPO ([64][16 slots][16B], slot ^= row&15)
  {
    unsigned w0 = cvtpk(s0[0], s0[1]), w1 = cvtpk(s0[2], s0[3]);
    unsigned w2 = cvtpk(s1[0], s1[1]), w3 = cvtpk(s1[2], s1[3]);
    unsigned w4 = cvtpk(s2[0], s2[1]), w5 = cvtpk(s2[2], s2[3]);
    unsigned w6 = cvtpk(s3[0], s3[1]), w7 = cvtpk(s3[2], s3[3]);
    *(u32x4*)(smem + SPO + srow * 256 + (((sq * 2 + 0) ^ (srow & 15)) << 4)) =
        (u32x4){w0, w1, w2, w3};
    *(u32x4*)(smem + SPO + srow * 256 + (((sq * 2 + 1) ^ (srow & 15)) << 4)) =
        (u32x4){w4, w5, w6, w7};
  }
  // x -> regs (bf16 pairs), ds-written after A phase
  unsigned xr[6];
  xr[0] = cvtpk(x0[0], x0[1]); xr[1] = cvtpk(x0[2], x0[3]);
  xr[2] = cvtpk(x1[0], x1[1]); xr[3] = cvtpk(x1[2], x1[3]);
  xr[4] = cvtpk(x2[0], x2[1]); xr[5] = cvtpk(x2[2], x2[3]);
#pragma unroll
  for (int kk = 0; kk < 8; ++kk) KEEP((int)b2f[kk][0]);
#pragma unroll
  for (int j = 0; j < 8; ++j) KEEP(invm[j]);
#pragma unroll
  for (int j = 0; j < 6; ++j) KEEP(xr[j]);
  KEEP(sCv);
  asm volatile("s_waitcnt vmcnt(0)" ::: "memory");
  LGKM_BAR();                                  // SPO published

  // counted stream: c0, then one chunk per step (2-slot ring, depth 1)
  gl_lds16(Wall + 0 * 4096 + wv * 512 + lane * 8, smem + RNG + 0 * 8192 + wv * 1024);

  const int woff = (wv * 16 + o) * 64;
  const int wslot = (g ^ (o & 3)) << 4;

  f32x4 acc[4], acc2[2];
#pragma unroll
  for (int rt = 0; rt < 4; ++rt) acc[rt] = (f32x4){0.f, 0.f, 0.f, 0.f};
  acc2[0] = (f32x4){0.f, 0.f, 0.f, 0.f};
  acc2[1] = (f32x4){0.f, 0.f, 0.f, 0.f};
  float eq[6] = {0.f, 0.f, 0.f, 0.f, 0.f, 0.f};

#define CSLICE(QX, IL) do { \
    unsigned wpair = *(const unsigned*)(smem + WMO + nloc * 256 + \
        (((IL) * 32 + q * 4) ^ ((nloc & 15) << 4))); \
    float wf0 = bf2f((unsigned short)wpair); \
    float wf1 = bf2f((unsigned short)(wpair >> 16)); \
    const int xb = SPO + nloc * 192 + ((QX) * 8 + (IL)) * 6; \
    _Pragma("unroll") \
    for (int m_ = 0; m_ < 3; ++m_) { \
      float xv = bf2f(*(const unsigned short*)(smem + xb + m_ * 2)); \
      eq[m_] += xv * wf0; eq[3 + m_] += xv * wf1; \
    } \
  } while (0)

  // ================= A phase: chunks 0..15 (inv cols then wemb cols) ====
#pragma unroll
  for (int s = 0; s < 16; ++s) {
    const int ks = s & 3;
    LGKM0();                                   // ring WAR guard
    gl_lds16(Wall + (size_t)(s + 1) * 4096 + wv * 512 + lane * 8,
             smem + RNG + ((s + 1) & 1) * 8192 + wv * 1024);
    WAITV(1);                                  // c_s landed
    __builtin_amdgcn_s_setprio(1);
    {
      bf16x8 b = *(const bf16x8*)(smem + RNG + (s & 1) * 8192 + woff + wslot);
#pragma unroll
      for (int rt = 0; rt < 4; ++rt) {
        int row = rt * 16 + o;
        bf16x8 a = *(const bf16x8*)(smem + SPO + row * 256 +
                                    (((ks * 4 + g) ^ (row & 15)) << 4));
        acc[rt] = MFMA(a, b, acc[rt]);
      }
    }
    if (s >= 4 && s < 12) {                    // interleaved B-inv, kk = s-4
      const int kk = s - 4;
      const int hp = (kk < 4) ? HP0 : HP1;
      const int kb = (kk & 3) * 64 + g * 16;
#pragma unroll
      for (int rt = 0; rt < 2; ++rt) {
        int row = rw * 32 + rt * 16 + o;
        bf16x8 hi = *(const bf16x8*)(smem + hp + row * 256 + (kb ^ ((row & 15) << 4)));
        acc2[rt] = MFMA(hi, b2f[kk], acc2[rt]);
      }
    }
    __builtin_amdgcn_s_setprio(0);
    if (ks == 3) {                             // col-group epilogue -> HP
      const int hp = ((s >> 2) & 1) ? HP1 : HP0;
      const int col = wv * 16 + o;
#pragma unroll
      for (int rt = 0; rt < 4; ++rt) {
#pragma unroll
        for (int rp = 0; rp < 2; ++rp) {
          unsigned w = cvtpk(silu_rs(acc[rt][rp * 2]), silu_rs(acc[rt][rp * 2 + 1]));
          int row0 = rt * 16 + g * 4 + rp * 2;
          *(unsigned short*)(smem + hp + row0 * 256 +
                             ((col * 2) ^ ((row0 & 15) << 4))) = (unsigned short)w;
          int row1 = row0 + 1;
          *(unsigned short*)(smem + hp + row1 * 256 +
                             ((col * 2) ^ ((row1 & 15) << 4))) = (unsigned short)(w >> 16);
        }
        acc[rt] = (f32x4){0.f, 0.f, 0.f, 0.f};
      }
      LGKM_BAR();                              // publish CG (s=3,7,11,15)
      if (s == 15) {                           // SPO free: x -> LDS
        const int xb = SPO + srow * 192 + sq * 24;
#pragma unroll
        for (int j = 0; j < 6; ++j)
          *(unsigned*)(smem + xb + j * 4) = xr[j];
      }
    }
  }

  // ================= B phase: chunks 16..47 (wemb GEMM) =================
#pragma unroll
  for (int s = 16; s < 48; ++s) {
    const int t = s - 16, kk = t & 7, QQ = t >> 3;
    LGKM0();
    if (s < 47)
      gl_lds16(Wall + (size_t)(s + 1) * 4096 + wv * 512 + lane * 8,
               smem + RNG + ((s + 1) & 1) * 8192 + wv * 1024);
    if (s < 47) WAITV(1); else WAITV(0);
    __builtin_amdgcn_s_setprio(1);
    {
      bf16x8 b = *(const bf16x8*)(smem + RNG + (s & 1) * 8192 + woff + wslot);
      const int hp = (kk < 4) ? HP0 : HP1;
      const int kb = (kk & 3) * 64 + g * 16;
#pragma unroll
      for (int rt = 0; rt < 4; ++rt) {
        int row = rt * 16 + o;
        bf16x8 h = *(const bf16x8*)(smem + hp + row * 256 + (kb ^ ((row & 15) << 4)));
        acc[rt] = MFMA(h, b, acc[rt]);
      }
    }
    __builtin_amdgcn_s_setprio(0);
    // phase-C: consume quarter QQ-1 at kk=0..6 (double slice at kk==6)
    if (t >= 8 && kk < 7) {
      CSLICE(QQ - 1, kk);
      if (kk == 6) CSLICE(QQ - 1, 7);
    }
    if (kk == 7) {                             // Wm quarter publish
      LGKM_BAR();    // r16 BUGFIX: all waves' prior-quarter reads complete
      const int lc = wv * 16 + o;
#pragma unroll
      for (int rt = 0; rt < 4; ++rt) {
#pragma unroll
        for (int rp = 0; rp < 2; ++rp) {
          unsigned w = cvtpk(acc[rt][rp * 2] * inv16, acc[rt][rp * 2 + 1] * inv16);
          int n0 = rt * 16 + g * 4 + rp * 2;
          *(unsigned short*)(smem + WMO + n0 * 256 +
                             ((lc * 2) ^ ((n0 & 15) << 4))) = (unsigned short)w;
          int n1 = n0 + 1;
          *(unsigned short*)(smem + WMO + n1 * 256 +
                             ((lc * 2) ^ ((n1 & 15) << 4))) = (unsigned short)(w >> 16);
        }
        acc[rt] = (f32x4){0.f, 0.f, 0.f, 0.f};
      }
      LGKM_BAR();                              // publish (t=7,15,23,31)
    }
  }

  // ---- epilogue: final quarter (QQ=3) + stores --------------------------
#pragma unroll
  for (int il = 0; il < 8; ++il) CSLICE(3, il);

#pragma unroll
  for (int rt = 0; rt < 2; ++rt)
#pragma unroll
    for (int r = 0; r < 4; ++r) {
      int node = base + rw * 32 + rt * 16 + g * 4 + r;
      if (node < NN)
        out[(size_t)node * OUTC + cw * 16 + o] = acc2[rt][r] * invm[rt * 4 + r];
    }
  if (base + nloc < NN) {
    float* op = out + (size_t)(base + nloc) * OUTC + 64 + q * 6;
#pragma unroll
    for (int j = 0; j < 6; ++j) op[j] = eq[j] * sCv;
  }
#undef CSLICE
}

// ---- launch ------------------------------------------------------------
extern "C" void kernel_launch(void* const* d_in, const int* in_sizes, int n_in,
                              void* d_out, int out_size, void* d_ws, size_t ws_size,
                              hipStream_t stream) {
  const float* feats = (const float*)d_in[0];
  const int* ei = (const int*)d_in[1];
  const float* invW1 = (const float*)d_in[2];
  const float* invW2 = (const float*)d_in[3];
  const float* wembW1 = (const float*)d_in[4];
  const float* wembW2 = (const float*)d_in[5];
  float* out = (float*)d_out;

  char* ws = (char*)d_ws;
  unsigned short* W1s = (unsigned short*)(ws);                    // 131072 B
  unsigned short* W2w = (unsigned short*)(ws + 131072);           // 262144 B
  unsigned short* W2i = (unsigned short*)(ws + 393216);           // 32768 B
  unsigned char* act  = (unsigned char*)(ws + 425984);            // 100096 B

  k_zero<<<98, 256, 0, stream>>>((unsigned int*)act, 25024);
  k_scatter<<<1563, 256, 0, stream>>>(ei, act);
  k_wprep<<<832, 256, 0, stream>>>(invW1, invW2, wembW1, wembW2, W1s, W2w, W2i);
  k_main<<<1563, 512, 0, stream>>>(feats, W1s, W2i, act, out);
}

// Round 18
// 153.518 us; speedup vs baseline: 1.0409x; 1.0409x over previous
//
#include <hip/hip_runtime.h>

#define NN 100000
#define EE 1600000
#define FDIM 224
#define OUTC 112

// LDS byte offsets (80KB total -> 2 blocks/CU)
#define SPO 0        // scalars [64][128] bf16 (16KB); after A: x_eq [64][96] bf16
#define HP0 16384    // H col-group ping (16KB)
#define HP1 32768    // H col-group pong (16KB)
#define RNG 49152    // weight ring: 2 x 8KB
#define WMO 65536    // Wm quarter (single buffer, 16KB)
#define LDSZ 81920

typedef __attribute__((ext_vector_type(8))) short bf16x8;
typedef __attribute__((ext_vector_type(8))) unsigned short u16x8;
typedef __attribute__((ext_vector_type(4))) float f32x4;
typedef __attribute__((ext_vector_type(4))) unsigned int u32x4;
typedef __attribute__((ext_vector_type(4))) int i32x4;

__device__ __forceinline__ unsigned short f2bf(float f) {
  unsigned u = __builtin_bit_cast(unsigned, f);
  u = (u + 0x7FFFu + ((u >> 16) & 1u)) >> 16;   // RNE
  return (unsigned short)u;
}
__device__ __forceinline__ float bf2f(unsigned short h) {
  return __builtin_bit_cast(float, (unsigned)h << 16);
}
__device__ __forceinline__ unsigned cvtpk(float lo, float hi) {
  unsigned d;
  asm("v_cvt_pk_bf16_f32 %0, %1, %2" : "=v"(d) : "v"(lo), "v"(hi));
  return d;
}
__device__ __forceinline__ float fast_exp2(float t) {
  float e; asm("v_exp_f32 %0, %1" : "=v"(e) : "v"(t)); return e;
}
__device__ __forceinline__ float fast_rcp(float x) {
  float r; asm("v_rcp_f32 %0, %1" : "=v"(r) : "v"(x)); return r;
}
__device__ __forceinline__ float silu_rs(float a) {     // silu(a / sqrt(128))
  float v = a * 0.08838834764831845f;
  float e = fast_exp2(v * -1.442695041f);
  return v * fast_rcp(1.f + e);
}
__device__ __forceinline__ void gl_lds16(const unsigned short* g, char* l) {
  __builtin_amdgcn_global_load_lds(
      (const __attribute__((address_space(1))) unsigned int*)g,
      (__attribute__((address_space(3))) unsigned int*)l, 16, 0, 0);
}

#define WAITV(n) do { asm volatile("s_waitcnt vmcnt(" #n ")" ::: "memory"); \
                      __builtin_amdgcn_sched_barrier(0); } while (0)
#define LGKM0() asm volatile("s_waitcnt lgkmcnt(0)" ::: "memory")
#define LGKM_BAR() do { asm volatile("s_waitcnt lgkmcnt(0)" ::: "memory"); \
                        __builtin_amdgcn_s_barrier(); } while (0)
#define KEEP(x) asm volatile("" :: "v"(x))
#define MFMA(A, B, C) __builtin_amdgcn_mfma_f32_16x16x32_bf16((A), (B), (C), 0, 0, 0)

// ---- prep kernels (proven) ----------------------------------------------
__global__ void k_zero(unsigned int* p, int n) {
  int i = blockIdx.x * 256 + threadIdx.x;
  if (i < n) p[i] = 0u;
}

__global__ void k_scatter(const int* __restrict__ ei, unsigned char* __restrict__ act) {
  int e4 = blockIdx.x * 256 + threadIdx.x;
  if (e4 < EE / 4) {
    i32x4 v = *(const i32x4*)(ei + e4 * 4);
#pragma unroll
    for (int j = 0; j < 4; ++j) {
      int n = v[j];
      if (!act[n]) act[n] = 1;
    }
  }
}

__global__ void k_wprep(const float* __restrict__ invW1, const float* __restrict__ invW2,
                        const float* __restrict__ wembW1, const float* __restrict__ wembW2,
                        unsigned short* __restrict__ W1s, unsigned short* __restrict__ W2w,
                        unsigned short* __restrict__ W2i) {
  int i = blockIdx.x * 256 + threadIdx.x;
  if (i < 65536) {
    int c = i >> 12, j = i & 4095;
    int r128 = j >> 5, slot = (j >> 3) & 3, e = j & 7;
    int gg = slot ^ (r128 & 3);
    int n = (c >> 2) * 128 + r128;
    int k = (c & 3) * 32 + gg * 8 + e;
    float v = (n < 256) ? invW1[k * 256 + n] : wembW1[k * 256 + (n - 256)];
    W1s[i] = f2bf(v);
  } else if (i < 196608) {
    int t = i - 65536;
    int c = t >> 12, j = t & 4095;
    int r128 = j >> 5, slot = (j >> 3) & 3, e = j & 7;
    int gg = slot ^ (r128 & 3);
    int n = (c >> 3) * 128 + r128;
    int k = (c & 7) * 32 + gg * 8 + e;
    W2w[t] = f2bf(wembW2[k * 512 + n]);
  } else if (i < 212992) {
    int t = i - 196608;
    int n = t >> 8, k = t & 255;
    W2i[t] = f2bf(invW2[k * 64 + n]);
  }
}

// ---- fused main kernel: BM=64, 48-step counted-vmcnt engine -------------
// 64 nodes/block, 512 thr (8 waves), LDS 80KB -> 2 blocks/CU. Grid 1563.
// r18: __launch_bounds__(512,2) -- VGPR cap 256 so the ~90-reg working set
// fits without scratch spill (LDS still caps occupancy at 2 blocks/CU).
__global__ __launch_bounds__(512, 2) void k_main(
    const float* __restrict__ feats,
    const unsigned short* __restrict__ Wall,   // W1s(0..15) ++ W2w(16..47)
    const unsigned short* __restrict__ W2i,
    const unsigned char* __restrict__ act,
    float* __restrict__ out) {
  __shared__ char smem[LDSZ];
  const int tid = threadIdx.x;
  const int lane = tid & 63;
  const int wv = tid >> 6;
  const int o = lane & 15;
  const int g = lane >> 4;
  const int base = blockIdx.x * 64;
  const int rw = wv & 1, cw = wv >> 1;        // inv tile roles (64x64)
  const int nloc = tid >> 3, q = tid & 7;     // phase-C roles (8 thr/node)

  const float inv16 = 0.0625f;
  const float rs32  = 0.17677669529663687f;

  // ---- prologue: all compiler loads issued, converted, drained ---------
  const int srow = tid >> 3, sq = tid & 7;
  int gnode = base + srow; if (gnode > NN - 1) gnode = NN - 1;
  const float* sp = feats + (size_t)gnode * FDIM + sq * 16;
  f32x4 s0 = *(const f32x4*)sp;
  f32x4 s1 = *(const f32x4*)(sp + 4);
  f32x4 s2 = *(const f32x4*)(sp + 8);
  f32x4 s3 = *(const f32x4*)(sp + 12);
  const float* xp = feats + (size_t)gnode * FDIM + 128 + sq * 12;
  f32x4 x0 = *(const f32x4*)xp;
  f32x4 x1 = *(const f32x4*)(xp + 4);
  f32x4 x2 = *(const f32x4*)(xp + 8);

  bf16x8 b2f[8];
#pragma unroll
  for (int kk = 0; kk < 8; ++kk)
    b2f[kk] = *(const bf16x8*)(W2i + (cw * 16 + o) * 256 + kk * 32 + g * 8);
  float invm[8];
#pragma unroll
  for (int rt = 0; rt < 2; ++rt)
#pragma unroll
    for (int r = 0; r < 4; ++r) {
      int node = base + rw * 32 + rt * 16 + g * 4 + r;
      invm[rt * 4 + r] = (node < NN && act[node < NN ? node : 0]) ? inv16 : 0.f;
    }
  const float sCv = (base + nloc < NN && act[base + nloc < NN ? base + nloc : 0]) ? rs32 : 0.f;

  // scalars -> SPO ([64][16 slots][16B], slot ^= row&15)
  {
    unsigned w0 = cvtpk(s0[0], s0[1]), w1 = cvtpk(s0[2], s0[3]);
    unsigned w2 = cvtpk(s1[0], s1[1]), w3 = cvtpk(s1[2], s1[3]);
    unsigned w4 = cvtpk(s2[0], s2[1]), w5 = cvtpk(s2[2], s2[3]);
    unsigned w6 = cvtpk(s3[0], s3[1]), w7 = cvtpk(s3[2], s3[3]);
    *(u32x4*)(smem + SPO + srow * 256 + (((sq * 2 + 0) ^ (srow & 15)) << 4)) =
        (u32x4){w0, w1, w2, w3};
    *(u32x4*)(smem + SPO + srow * 256 + (((sq * 2 + 1) ^ (srow & 15)) << 4)) =
        (u32x4){w4, w5, w6, w7};
  }
  // x -> regs (bf16 pairs), ds-written after A phase
  unsigned xr[6];
  xr[0] = cvtpk(x0[0], x0[1]); xr[1] = cvtpk(x0[2], x0[3]);
  xr[2] = cvtpk(x1[0], x1[1]); xr[3] = cvtpk(x1[2], x1[3]);
  xr[4] = cvtpk(x2[0], x2[1]); xr[5] = cvtpk(x2[2], x2[3]);
#pragma unroll
  for (int kk = 0; kk < 8; ++kk) KEEP((int)b2f[kk][0]);
#pragma unroll
  for (int j = 0; j < 8; ++j) KEEP(invm[j]);
#pragma unroll
  for (int j = 0; j < 6; ++j) KEEP(xr[j]);
  KEEP(sCv);
  asm volatile("s_waitcnt vmcnt(0)" ::: "memory");
  LGKM_BAR();                                  // SPO published

  // counted stream: c0, then one chunk per step (2-slot ring, depth 1)
  gl_lds16(Wall + 0 * 4096 + wv * 512 + lane * 8, smem + RNG + 0 * 8192 + wv * 1024);

  const int woff = (wv * 16 + o) * 64;
  const int wslot = (g ^ (o & 3)) << 4;

  f32x4 acc[4], acc2[2];
#pragma unroll
  for (int rt = 0; rt < 4; ++rt) acc[rt] = (f32x4){0.f, 0.f, 0.f, 0.f};
  acc2[0] = (f32x4){0.f, 0.f, 0.f, 0.f};
  acc2[1] = (f32x4){0.f, 0.f, 0.f, 0.f};
  float eq[6] = {0.f, 0.f, 0.f, 0.f, 0.f, 0.f};

#define CSLICE(QX, IL) do { \
    unsigned wpair = *(const unsigned*)(smem + WMO + nloc * 256 + \
        (((IL) * 32 + q * 4) ^ ((nloc & 15) << 4))); \
    float wf0 = bf2f((unsigned short)wpair); \
    float wf1 = bf2f((unsigned short)(wpair >> 16)); \
    const int xb = SPO + nloc * 192 + ((QX) * 8 + (IL)) * 6; \
    _Pragma("unroll") \
    for (int m_ = 0; m_ < 3; ++m_) { \
      float xv = bf2f(*(const unsigned short*)(smem + xb + m_ * 2)); \
      eq[m_] += xv * wf0; eq[3 + m_] += xv * wf1; \
    } \
  } while (0)

  // ================= A phase: chunks 0..15 (inv cols then wemb cols) ====
#pragma unroll
  for (int s = 0; s < 16; ++s) {
    const int ks = s & 3;
    LGKM0();                                   // ring WAR guard
    gl_lds16(Wall + (size_t)(s + 1) * 4096 + wv * 512 + lane * 8,
             smem + RNG + ((s + 1) & 1) * 8192 + wv * 1024);
    WAITV(1);                                  // c_s landed
    __builtin_amdgcn_s_setprio(1);
    {
      bf16x8 b = *(const bf16x8*)(smem + RNG + (s & 1) * 8192 + woff + wslot);
#pragma unroll
      for (int rt = 0; rt < 4; ++rt) {
        int row = rt * 16 + o;
        bf16x8 a = *(const bf16x8*)(smem + SPO + row * 256 +
                                    (((ks * 4 + g) ^ (row & 15)) << 4));
        acc[rt] = MFMA(a, b, acc[rt]);
      }
    }
    if (s >= 4 && s < 12) {                    // interleaved B-inv, kk = s-4
      const int kk = s - 4;
      const int hp = (kk < 4) ? HP0 : HP1;
      const int kb = (kk & 3) * 64 + g * 16;
#pragma unroll
      for (int rt = 0; rt < 2; ++rt) {
        int row = rw * 32 + rt * 16 + o;
        bf16x8 hi = *(const bf16x8*)(smem + hp + row * 256 + (kb ^ ((row & 15) << 4)));
        acc2[rt] = MFMA(hi, b2f[kk], acc2[rt]);
      }
    }
    __builtin_amdgcn_s_setprio(0);
    if (ks == 3) {                             // col-group epilogue -> HP
      const int hp = ((s >> 2) & 1) ? HP1 : HP0;
      const int col = wv * 16 + o;
#pragma unroll
      for (int rt = 0; rt < 4; ++rt) {
#pragma unroll
        for (int rp = 0; rp < 2; ++rp) {
          unsigned w = cvtpk(silu_rs(acc[rt][rp * 2]), silu_rs(acc[rt][rp * 2 + 1]));
          int row0 = rt * 16 + g * 4 + rp * 2;
          *(unsigned short*)(smem + hp + row0 * 256 +
                             ((col * 2) ^ ((row0 & 15) << 4))) = (unsigned short)w;
          int row1 = row0 + 1;
          *(unsigned short*)(smem + hp + row1 * 256 +
                             ((col * 2) ^ ((row1 & 15) << 4))) = (unsigned short)(w >> 16);
        }
        acc[rt] = (f32x4){0.f, 0.f, 0.f, 0.f};
      }
      LGKM_BAR();                              // publish CG (s=3,7,11,15)
      if (s == 15) {                           // SPO free: x -> LDS
        const int xb = SPO + srow * 192 + sq * 24;
#pragma unroll
        for (int j = 0; j < 6; ++j)
          *(unsigned*)(smem + xb + j * 4) = xr[j];
      }
    }
  }

  // ================= B phase: chunks 16..47 (wemb GEMM) =================
#pragma unroll
  for (int s = 16; s < 48; ++s) {
    const int t = s - 16, kk = t & 7, QQ = t >> 3;
    LGKM0();
    if (s < 47)
      gl_lds16(Wall + (size_t)(s + 1) * 4096 + wv * 512 + lane * 8,
               smem + RNG + ((s + 1) & 1) * 8192 + wv * 1024);
    if (s < 47) WAITV(1); else WAITV(0);
    __builtin_amdgcn_s_setprio(1);
    {
      bf16x8 b = *(const bf16x8*)(smem + RNG + (s & 1) * 8192 + woff + wslot);
      const int hp = (kk < 4) ? HP0 : HP1;
      const int kb = (kk & 3) * 64 + g * 16;
#pragma unroll
      for (int rt = 0; rt < 4; ++rt) {
        int row = rt * 16 + o;
        bf16x8 h = *(const bf16x8*)(smem + hp + row * 256 + (kb ^ ((row & 15) << 4)));
        acc[rt] = MFMA(h, b, acc[rt]);
      }
    }
    __builtin_amdgcn_s_setprio(0);
    // phase-C: consume quarter QQ-1 at kk=0..6 (double slice at kk==6)
    if (t >= 8 && kk < 7) {
      CSLICE(QQ - 1, kk);
      if (kk == 6) CSLICE(QQ - 1, 7);
    }
    if (kk == 7) {                             // Wm quarter publish
      LGKM_BAR();    // all waves' prior-quarter reads complete
      const int lc = wv * 16 + o;
#pragma unroll
      for (int rt = 0; rt < 4; ++rt) {
#pragma unroll
        for (int rp = 0; rp < 2; ++rp) {
          unsigned w = cvtpk(acc[rt][rp * 2] * inv16, acc[rt][rp * 2 + 1] * inv16);
          int n0 = rt * 16 + g * 4 + rp * 2;
          *(unsigned short*)(smem + WMO + n0 * 256 +
                             ((lc * 2) ^ ((n0 & 15) << 4))) = (unsigned short)w;
          int n1 = n0 + 1;
          *(unsigned short*)(smem + WMO + n1 * 256 +
                             ((lc * 2) ^ ((n1 & 15) << 4))) = (unsigned short)(w >> 16);
        }
        acc[rt] = (f32x4){0.f, 0.f, 0.f, 0.f};
      }
      LGKM_BAR();                              // publish (t=7,15,23,31)
    }
  }

  // ---- epilogue: final quarter (QQ=3) + stores --------------------------
#pragma unroll
  for (int il = 0; il < 8; ++il) CSLICE(3, il);

#pragma unroll
  for (int rt = 0; rt < 2; ++rt)
#pragma unroll
    for (int r = 0; r < 4; ++r) {
      int node = base + rw * 32 + rt * 16 + g * 4 + r;
      if (node < NN)
        out[(size_t)node * OUTC + cw * 16 + o] = acc2[rt][r] * invm[rt * 4 + r];
    }
  if (base + nloc < NN) {
    float* op = out + (size_t)(base + nloc) * OUTC + 64 + q * 6;
#pragma unroll
    for (int j = 0; j < 6; ++j) op[j] = eq[j] * sCv;
  }
#undef CSLICE
}

// ---- launch ------------------------------------------------------------
extern "C" void kernel_launch(void* const* d_in, const int* in_sizes, int n_in,
                              void* d_out, int out_size, void* d_ws, size_t ws_size,
                              hipStream_t stream) {
  const float* feats = (const float*)d_in[0];
  const int* ei = (const int*)d_in[1];
  const float* invW1 = (const float*)d_in[2];
  const float* invW2 = (const float*)d_in[3];
  const float* wembW1 = (const float*)d_in[4];
  const float* wembW2 = (const float*)d_in[5];
  float* out = (float*)d_out;

  char* ws = (char*)d_ws;
  unsigned short* W1s = (unsigned short*)(ws);                    // 131072 B
  unsigned short* W2w = (unsigned short*)(ws + 131072);           // 262144 B
  unsigned short* W2i = (unsigned short*)(ws + 393216);           // 32768 B
  unsigned char* act  = (unsigned char*)(ws + 425984);            // 100096 B

  k_zero<<<98, 256, 0, stream>>>((unsigned int*)act, 25024);
  k_scatter<<<1563, 256, 0, stream>>>(ei, act);
  k_wprep<<<832, 256, 0, stream>>>(invW1, invW2, wembW1, wembW2, W1s, W2w, W2i);
  k_main<<<1563, 512, 0, stream>>>(feats, W1s, W2i, act, out);
}

// Round 19
// 132.266 us; speedup vs baseline: 1.2081x; 1.1607x over previous
//
#include <hip/hip_runtime.h>

#define NN 100000
#define EE 1600000
#define FDIM 224
#define OUTC 112

// LDS byte offsets (80KB)
#define SPO 0        // scalars [64][16 slots][16B] bf16, slot ^= row&15 (16KB)
#define HCG 16384    // H col-group [64 rows][128 cols bf16], 256B rows (16KB)
#define RNG 32768    // weight ring: 4 x 8KB (32KB)
#define XO  32768    // tail: x_eq [64][96] bf16 (12KB, reuses ring slot 0)
#define WMO 65536    // tail: Wm quarter (16KB)
#define LDSZ 81920

typedef __attribute__((ext_vector_type(8))) short bf16x8;
typedef __attribute__((ext_vector_type(4))) float f32x4;
typedef __attribute__((ext_vector_type(4))) unsigned int u32x4;
typedef __attribute__((ext_vector_type(4))) int i32x4;

__device__ __forceinline__ unsigned short f2bf(float f) {
  unsigned u = __builtin_bit_cast(unsigned, f);
  u = (u + 0x7FFFu + ((u >> 16) & 1u)) >> 16;   // RNE
  return (unsigned short)u;
}
__device__ __forceinline__ float bf2f(unsigned short h) {
  return __builtin_bit_cast(float, (unsigned)h << 16);
}
__device__ __forceinline__ unsigned cvtpk(float lo, float hi) {
  unsigned d;
  asm("v_cvt_pk_bf16_f32 %0, %1, %2" : "=v"(d) : "v"(lo), "v"(hi));
  return d;
}
__device__ __forceinline__ float fast_exp2(float t) {
  float e; asm("v_exp_f32 %0, %1" : "=v"(e) : "v"(t)); return e;
}
__device__ __forceinline__ float fast_rcp(float x) {
  float r; asm("v_rcp_f32 %0, %1" : "=v"(r) : "v"(x)); return r;
}
__device__ __forceinline__ float silu_rs(float a) {     // silu(a / sqrt(128))
  float v = a * 0.08838834764831845f;
  float e = fast_exp2(v * -1.442695041f);
  return v * fast_rcp(1.f + e);
}
__device__ __forceinline__ void gl_lds16(const unsigned short* g, char* l) {
  __builtin_amdgcn_global_load_lds(
      (const __attribute__((address_space(1))) unsigned int*)g,
      (__attribute__((address_space(3))) unsigned int*)l, 16, 0, 0);
}

#define WAITV(n) do { asm volatile("s_waitcnt vmcnt(" #n ")" ::: "memory"); \
                      __builtin_amdgcn_sched_barrier(0); } while (0)
#define WAITV_FOR(c) do { if ((c) <= 52) { WAITV(3); } else if ((c) == 53) { WAITV(2); } \
                          else if ((c) == 54) { WAITV(1); } else { WAITV(0); } } while (0)
#define LGKM0() asm volatile("s_waitcnt lgkmcnt(0)" ::: "memory")
#define LGKM_BAR() do { asm volatile("s_waitcnt lgkmcnt(0)" ::: "memory"); \
                        __builtin_amdgcn_s_barrier(); } while (0)
#define KEEP(x) asm volatile("" :: "v"(x))
#define MFMA(A, B, C) __builtin_amdgcn_mfma_f32_16x16x32_bf16((A), (B), (C), 0, 0, 0)
#define ISSUE(c) do { if ((c) < 56) \
    gl_lds16(Wall + (size_t)(c) * 4096 + wv * 512 + lane * 8, \
             smem + RNG + ((c) & 3) * 8192 + wv * 1024); } while (0)

// ---- prep kernels -------------------------------------------------------
__global__ void k_zero(unsigned int* p, int n) {
  int i = blockIdx.x * 256 + threadIdx.x;
  if (i < n) p[i] = 0u;
}

__global__ void k_scatter(const int* __restrict__ ei, unsigned char* __restrict__ act) {
  int e4 = blockIdx.x * 256 + threadIdx.x;
  if (e4 < EE / 4) {
    i32x4 v = *(const i32x4*)(ei + e4 * 4);
#pragma unroll
    for (int j = 0; j < 4; ++j) {
      int n = v[j];
      if (!act[n]) act[n] = 1;
    }
  }
}

// 56-chunk stream. cg0: c0..3 W1, c4..7 inv | cg1: c8..11 W1, c12..15 inv |
// cg2: c16..19 W1, c20..35 W2w | cg3: c36..39 W1, c40..55 W2w.
// W1/W2w chunk: 128 rows x 32 K; u16 idx = r128*32 + slot*8 + e, gg = slot^(r128&3).
// inv chunk: 8 wave-segs of 512 u16; seg: r16*32 + slot*8 + e, gg = slot^(r16&3),
//            col = (wseg>>1)*16 + r16 (wave pairs duplicated).
__global__ void k_wprep(const float* __restrict__ invW1, const float* __restrict__ invW2,
                        const float* __restrict__ wembW1, const float* __restrict__ wembW2,
                        unsigned short* __restrict__ Wall) {
  int i = blockIdx.x * 256 + threadIdx.x;
  if (i >= 56 * 4096) return;
  int c = i >> 12, j = i & 4095;
  float v;
  if (c < 16) {
    int cg = c >> 3, sub = c & 7;
    if (sub < 4) {                         // W1 (H-cols cg*128..)
      int r128 = j >> 5, slot = (j >> 3) & 3, e = j & 7;
      int gg = slot ^ (r128 & 3);
      int hc = cg * 128 + r128;
      int k = sub * 32 + gg * 8 + e;
      v = (hc < 256) ? invW1[k * 256 + hc] : wembW1[k * 256 + (hc - 256)];
    } else {                               // invW2 K-slice cg*128..
      int ks = sub - 4;
      int wseg = j >> 9, r16 = (j >> 5) & 15, slot = (j >> 3) & 3, e = j & 7;
      int gg = slot ^ (r16 & 3);
      int col = (wseg >> 1) * 16 + r16;
      int k = cg * 128 + ks * 32 + gg * 8 + e;
      v = invW2[k * 64 + col];
    }
  } else {
    int c2 = c - 16;
    int cgl = c2 / 20, sub = c2 % 20;      // cgl 0,1 -> cg 2,3
    int r128 = j >> 5, slot = (j >> 3) & 3, e = j & 7;
    int gg = slot ^ (r128 & 3);
    if (sub < 4) {                         // W1 (H-cols (2+cgl)*128..)
      int hc = (2 + cgl) * 128 + r128;
      int k = sub * 32 + gg * 8 + e;
      v = (hc < 256) ? invW1[k * 256 + hc] : wembW1[k * 256 + (hc - 256)];
    } else {                               // wembW2 K-slice cgl*128..
      int idx = sub - 4, ct = idx >> 2, ks = idx & 3;
      int col = ct * 128 + r128;
      int k = cgl * 128 + ks * 32 + gg * 8 + e;
      v = wembW2[k * 512 + col];
    }
  }
  Wall[i] = f2bf(v);
}

// ---- fused main kernel: acc-resident, 4-deep ring, 56 chunk-steps -------
// 64 nodes/block, 512 thr (8 waves), LDS 80KB. Grid 1563.
__global__ __launch_bounds__(512, 2) void k_main(
    const float* __restrict__ feats,
    const unsigned short* __restrict__ Wall,
    const unsigned char* __restrict__ act,
    float* __restrict__ out) {
  __shared__ char smem[LDSZ];
  const int tid = threadIdx.x;
  const int lane = tid & 63;
  const int wv = tid >> 6;
  const int o = lane & 15;
  const int g = lane >> 4;
  const int base = blockIdx.x * 64;

  const float inv16 = 0.0625f;
  const float rs32  = 0.17677669529663687f;

  // ---- prologue: S + x loads, convert, stage S; drain before stream ----
  const int srow = tid >> 3, sq = tid & 7;
  int gnode = base + srow; if (gnode > NN - 1) gnode = NN - 1;
  const float* sp = feats + (size_t)gnode * FDIM + sq * 16;
  f32x4 s0 = *(const f32x4*)sp;
  f32x4 s1 = *(const f32x4*)(sp + 4);
  f32x4 s2 = *(const f32x4*)(sp + 8);
  f32x4 s3 = *(const f32x4*)(sp + 12);
  const float* xp = feats + (size_t)gnode * FDIM + 128 + sq * 12;
  f32x4 x0 = *(const f32x4*)xp;
  f32x4 x1 = *(const f32x4*)(xp + 4);
  f32x4 x2 = *(const f32x4*)(xp + 8);

  {
    unsigned w0 = cvtpk(s0[0], s0[1]), w1 = cvtpk(s0[2], s0[3]);
    unsigned w2 = cvtpk(s1[0], s1[1]), w3 = cvtpk(s1[2], s1[3]);
    unsigned w4 = cvtpk(s2[0], s2[1]), w5 = cvtpk(s2[2], s2[3]);
    unsigned w6 = cvtpk(s3[0], s3[1]), w7 = cvtpk(s3[2], s3[3]);
    *(u32x4*)(smem + SPO + srow * 256 + (((sq * 2 + 0) ^ (srow & 15)) << 4)) =
        (u32x4){w0, w1, w2, w3};
    *(u32x4*)(smem + SPO + srow * 256 + (((sq * 2 + 1) ^ (srow & 15)) << 4)) =
        (u32x4){w4, w5, w6, w7};
  }
  unsigned xr[6];
  xr[0] = cvtpk(x0[0], x0[1]); xr[1] = cvtpk(x0[2], x0[3]);
  xr[2] = cvtpk(x1[0], x1[1]); xr[3] = cvtpk(x1[2], x1[3]);
  xr[4] = cvtpk(x2[0], x2[1]); xr[5] = cvtpk(x2[2], x2[3]);
#pragma unroll
  for (int j = 0; j < 6; ++j) KEEP(xr[j]);
  asm volatile("s_waitcnt vmcnt(0)" ::: "memory");
  LGKM_BAR();                              // SPO published

  ISSUE(0); ISSUE(1); ISSUE(2); ISSUE(3);  // ring depth 4

  f32x4 accW[4][4], accA[4], acc2[2];
#pragma unroll
  for (int ct = 0; ct < 4; ++ct)
#pragma unroll
    for (int rt = 0; rt < 4; ++rt) accW[ct][rt] = (f32x4){0.f, 0.f, 0.f, 0.f};
#pragma unroll
  for (int rt = 0; rt < 4; ++rt) accA[rt] = (f32x4){0.f, 0.f, 0.f, 0.f};
  acc2[0] = (f32x4){0.f, 0.f, 0.f, 0.f};
  acc2[1] = (f32x4){0.f, 0.f, 0.f, 0.f};

  // ================= 4 col-groups ======================================
#pragma unroll
  for (int cg = 0; cg < 4; ++cg) {
    const int cb = (cg < 2) ? cg * 8 : 16 + (cg - 2) * 20;
    // ---- A: H_cg = silu(S @ W1 panel), 4 chunks -----------------------
#pragma unroll
    for (int ks = 0; ks < 4; ++ks) {
      const int c = cb + ks;
      WAITV_FOR(c);
      __builtin_amdgcn_s_setprio(1);
      bf16x8 b = *(const bf16x8*)(smem + RNG + (c & 3) * 8192 +
                                  (wv * 16 + o) * 64 + ((g ^ (o & 3)) << 4));
#pragma unroll
      for (int rt = 0; rt < 4; ++rt) {
        bf16x8 a = *(const bf16x8*)(smem + SPO + (rt * 16 + o) * 256 +
                                    (((ks * 4 + g) ^ o) << 4));
        accA[rt] = MFMA(a, b, accA[rt]);
      }
      __builtin_amdgcn_s_setprio(0);
      LGKM0();
      ISSUE(c + 4);
    }
    // A epilogue: silu -> HCG (wave's col = wv*16+o)
    {
      const int col = wv * 16 + o;
#pragma unroll
      for (int rt = 0; rt < 4; ++rt) {
#pragma unroll
        for (int rp = 0; rp < 2; ++rp) {
          unsigned w = cvtpk(silu_rs(accA[rt][rp * 2]), silu_rs(accA[rt][rp * 2 + 1]));
          int row0 = rt * 16 + g * 4 + rp * 2;
          *(unsigned short*)(smem + HCG + row0 * 256 +
                             ((col * 2) ^ ((row0 & 15) << 4))) = (unsigned short)w;
          int row1 = row0 + 1;
          *(unsigned short*)(smem + HCG + row1 * 256 +
                             ((col * 2) ^ ((row1 & 15) << 4))) = (unsigned short)(w >> 16);
        }
        accA[rt] = (f32x4){0.f, 0.f, 0.f, 0.f};
      }
    }
    LGKM_BAR();                            // publish H_cg
    // ---- B: contract H_cg against this cg's weight K-slice ------------
    if (cg < 2) {                          // inv: 4 chunks
#pragma unroll
      for (int ks = 0; ks < 4; ++ks) {
        const int c = cb + 4 + ks;
        WAITV_FOR(c);
        __builtin_amdgcn_s_setprio(1);
        bf16x8 b = *(const bf16x8*)(smem + RNG + (c & 3) * 8192 + wv * 1024 +
                                    o * 64 + ((g ^ (o & 3)) << 4));
        const int rtl = wv & 1;
        bf16x8 a0 = *(const bf16x8*)(smem + HCG + (rtl * 16 + o) * 256 +
                                     (((ks * 4 + g) ^ o) << 4));
        bf16x8 a1 = *(const bf16x8*)(smem + HCG + ((rtl + 2) * 16 + o) * 256 +
                                     (((ks * 4 + g) ^ o) << 4));
        acc2[0] = MFMA(a0, b, acc2[0]);
        acc2[1] = MFMA(a1, b, acc2[1]);
        __builtin_amdgcn_s_setprio(0);
        LGKM0();
        ISSUE(c + 4);
      }
    } else {                               // wemb: 16 chunks (ct x ks)
#pragma unroll
      for (int ct = 0; ct < 4; ++ct)
#pragma unroll
        for (int ks = 0; ks < 4; ++ks) {
          const int c = cb + 4 + ct * 4 + ks;
          WAITV_FOR(c);
          __builtin_amdgcn_s_setprio(1);
          bf16x8 b = *(const bf16x8*)(smem + RNG + (c & 3) * 8192 +
                                      (wv * 16 + o) * 64 + ((g ^ (o & 3)) << 4));
#pragma unroll
          for (int rt = 0; rt < 4; ++rt) {
            bf16x8 a = *(const bf16x8*)(smem + HCG + (rt * 16 + o) * 256 +
                                        (((ks * 4 + g) ^ o) << 4));
            accW[ct][rt] = MFMA(a, b, accW[ct][rt]);
          }
          __builtin_amdgcn_s_setprio(0);
          LGKM0();
          ISSUE(c + 4);
        }
    }
    LGKM_BAR();                            // cg end: H_cg readers done
  }

  // ================= tail: phase C from acc-resident Wm =================
  {
    const int xb = XO + srow * 192 + sq * 24;
#pragma unroll
    for (int j = 0; j < 6; ++j) *(unsigned*)(smem + xb + j * 4) = xr[j];
  }
  float eq[6] = {0.f, 0.f, 0.f, 0.f, 0.f, 0.f};
  const int nloc = tid >> 3, q = tid & 7;
#pragma unroll
  for (int Q = 0; Q < 4; ++Q) {
    const int lc = wv * 16 + o;
#pragma unroll
    for (int rt = 0; rt < 4; ++rt)
#pragma unroll
      for (int rp = 0; rp < 2; ++rp) {
        unsigned w = cvtpk(accW[Q][rt][rp * 2] * inv16, accW[Q][rt][rp * 2 + 1] * inv16);
        int n0 = rt * 16 + g * 4 + rp * 2;
        *(unsigned short*)(smem + WMO + n0 * 256 +
                           ((lc * 2) ^ ((n0 & 15) << 4))) = (unsigned short)w;
        int n1 = n0 + 1;
        *(unsigned short*)(smem + WMO + n1 * 256 +
                           ((lc * 2) ^ ((n1 & 15) << 4))) = (unsigned short)(w >> 16);
      }
    LGKM_BAR();                            // publish quarter (and XO at Q=0)
#pragma unroll
    for (int il = 0; il < 8; ++il) {
      unsigned wpair = *(const unsigned*)(smem + WMO + nloc * 256 +
                                          ((il * 32 + q * 4) ^ ((nloc & 15) << 4)));
      float wf0 = bf2f((unsigned short)wpair);
      float wf1 = bf2f((unsigned short)(wpair >> 16));
      const int xb = XO + nloc * 192 + (Q * 24 + il * 3) * 2;
#pragma unroll
      for (int m = 0; m < 3; ++m) {
        float xv = bf2f(*(const unsigned short*)(smem + xb + m * 2));
        eq[m] += xv * wf0;
        eq[3 + m] += xv * wf1;
      }
    }
    if (Q < 3) LGKM_BAR();                 // quarter readers done
  }

  // ---- final stores ----------------------------------------------------
#pragma unroll
  for (int jj = 0; jj < 2; ++jj) {
    const int rt = (wv & 1) + jj * 2;
#pragma unroll
    for (int r = 0; r < 4; ++r) {
      int node = base + rt * 16 + g * 4 + r;
      if (node < NN) {
        float s = act[node] ? inv16 : 0.f;
        out[(size_t)node * OUTC + (wv >> 1) * 16 + o] = acc2[jj][r] * s;
      }
    }
  }
  {
    int node = base + nloc;
    if (node < NN) {
      float sC = act[node] ? rs32 : 0.f;
      float* op = out + (size_t)node * OUTC + 64 + q * 6;
#pragma unroll
      for (int j = 0; j < 6; ++j) op[j] = eq[j] * sC;
    }
  }
}

// ---- launch ------------------------------------------------------------
extern "C" void kernel_launch(void* const* d_in, const int* in_sizes, int n_in,
                              void* d_out, int out_size, void* d_ws, size_t ws_size,
                              hipStream_t stream) {
  const float* feats = (const float*)d_in[0];
  const int* ei = (const int*)d_in[1];
  const float* invW1 = (const float*)d_in[2];
  const float* invW2 = (const float*)d_in[3];
  const float* wembW1 = (const float*)d_in[4];
  const float* wembW2 = (const float*)d_in[5];
  float* out = (float*)d_out;

  char* ws = (char*)d_ws;
  unsigned short* Wall = (unsigned short*)ws;                 // 458752 B
  unsigned char* act = (unsigned char*)(ws + 458752);         // 100096 B

  k_zero<<<98, 256, 0, stream>>>((unsigned int*)act, 25024);
  k_scatter<<<1563, 256, 0, stream>>>(ei, act);
  k_wprep<<<896, 256, 0, stream>>>(invW1, invW2, wembW1, wembW2, Wall);
  k_main<<<1563, 512, 0, stream>>>(feats, Wall, act, out);
}

// Round 20
// 116.576 us; speedup vs baseline: 1.3707x; 1.1346x over previous
//
#include <hip/hip_runtime.h>

#define NN 100000
#define EE 1600000
#define FDIM 224
#define OUTC 112

// LDS byte offsets (48KB -> 2 blocks/CU by LDS)
#define SPO 0        // scalars [32][16 slots][16B] bf16, slot ^= row&15 (8KB)
#define HCG 8192     // H col-group [32 rows][128 cols bf16], 256B rows (8KB)
#define RNG 16384    // weight ring: 4 x 8KB (32KB)
#define XO  16384    // tail: x_eq [32][96] bf16 (6KB, reuses ring slot 0)
#define WMQ 24576    // tail: Wm quarter [32][128] bf16 (8KB, ring slot 1)
#define LDSZ 49152

typedef __attribute__((ext_vector_type(8))) short bf16x8;
typedef __attribute__((ext_vector_type(4))) float f32x4;
typedef __attribute__((ext_vector_type(2))) float f32x2;
typedef __attribute__((ext_vector_type(4))) unsigned int u32x4;
typedef __attribute__((ext_vector_type(4))) int i32x4;

__device__ __forceinline__ unsigned short f2bf(float f) {
  unsigned u = __builtin_bit_cast(unsigned, f);
  u = (u + 0x7FFFu + ((u >> 16) & 1u)) >> 16;   // RNE
  return (unsigned short)u;
}
__device__ __forceinline__ float bf2f(unsigned short h) {
  return __builtin_bit_cast(float, (unsigned)h << 16);
}
__device__ __forceinline__ unsigned cvtpk(float lo, float hi) {
  unsigned d;
  asm("v_cvt_pk_bf16_f32 %0, %1, %2" : "=v"(d) : "v"(lo), "v"(hi));
  return d;
}
__device__ __forceinline__ float fast_exp2(float t) {
  float e; asm("v_exp_f32 %0, %1" : "=v"(e) : "v"(t)); return e;
}
__device__ __forceinline__ float fast_rcp(float x) {
  float r; asm("v_rcp_f32 %0, %1" : "=v"(r) : "v"(x)); return r;
}
__device__ __forceinline__ float silu_rs(float a) {     // silu(a / sqrt(128))
  float v = a * 0.08838834764831845f;
  float e = fast_exp2(v * -1.442695041f);
  return v * fast_rcp(1.f + e);
}
__device__ __forceinline__ void gl_lds16(const unsigned short* g, char* l) {
  __builtin_amdgcn_global_load_lds(
      (const __attribute__((address_space(1))) unsigned int*)g,
      (__attribute__((address_space(3))) unsigned int*)l, 16, 0, 0);
}

#define WAITV(n) do { asm volatile("s_waitcnt vmcnt(" #n ")" ::: "memory"); \
                      __builtin_amdgcn_sched_barrier(0); } while (0)
#define WAITV_FOR(c) do { if ((c) <= 52) { WAITV(3); } else if ((c) == 53) { WAITV(2); } \
                          else if ((c) == 54) { WAITV(1); } else { WAITV(0); } } while (0)
#define LGKM0() asm volatile("s_waitcnt lgkmcnt(0)" ::: "memory")
#define LGKM_BAR() do { asm volatile("s_waitcnt lgkmcnt(0)" ::: "memory"); \
                        __builtin_amdgcn_s_barrier(); } while (0)
#define KEEP(x) asm volatile("" :: "v"(x))
#define MFMA(A, B, C) __builtin_amdgcn_mfma_f32_16x16x32_bf16((A), (B), (C), 0, 0, 0)
#define ISSUE(c) do { if ((c) < 56) \
    gl_lds16(Wall + (size_t)(c) * 4096 + wv * 512 + lane * 8, \
             smem + RNG + ((c) & 3) * 8192 + wv * 1024); } while (0)

// ---- prep kernels -------------------------------------------------------
__global__ void k_zero(unsigned int* p, int n) {
  int i = blockIdx.x * 256 + threadIdx.x;
  if (i < n) p[i] = 0u;
}

__global__ void k_scatter(const int* __restrict__ ei, unsigned char* __restrict__ act) {
  int e4 = blockIdx.x * 256 + threadIdx.x;
  if (e4 < EE / 4) {
    i32x4 v = *(const i32x4*)(ei + e4 * 4);
#pragma unroll
    for (int j = 0; j < 4; ++j) {
      int n = v[j];
      if (!act[n]) act[n] = 1;
    }
  }
}

// 56-chunk stream (UNCHANGED from r19 — weights don't depend on BM).
__global__ void k_wprep(const float* __restrict__ invW1, const float* __restrict__ invW2,
                        const float* __restrict__ wembW1, const float* __restrict__ wembW2,
                        unsigned short* __restrict__ Wall) {
  int i = blockIdx.x * 256 + threadIdx.x;
  if (i >= 56 * 4096) return;
  int c = i >> 12, j = i & 4095;
  float v;
  if (c < 16) {
    int cg = c >> 3, sub = c & 7;
    if (sub < 4) {                         // W1 (H-cols cg*128..)
      int r128 = j >> 5, slot = (j >> 3) & 3, e = j & 7;
      int gg = slot ^ (r128 & 3);
      int hc = cg * 128 + r128;
      int k = sub * 32 + gg * 8 + e;
      v = (hc < 256) ? invW1[k * 256 + hc] : wembW1[k * 256 + (hc - 256)];
    } else {                               // invW2 K-slice cg*128..
      int ks = sub - 4;
      int wseg = j >> 9, r16 = (j >> 5) & 15, slot = (j >> 3) & 3, e = j & 7;
      int gg = slot ^ (r16 & 3);
      int col = (wseg >> 1) * 16 + r16;
      int k = cg * 128 + ks * 32 + gg * 8 + e;
      v = invW2[k * 64 + col];
    }
  } else {
    int c2 = c - 16;
    int cgl = c2 / 20, sub = c2 % 20;      // cgl 0,1 -> cg 2,3
    int r128 = j >> 5, slot = (j >> 3) & 3, e = j & 7;
    int gg = slot ^ (r128 & 3);
    if (sub < 4) {                         // W1 (H-cols (2+cgl)*128..)
      int hc = (2 + cgl) * 128 + r128;
      int k = sub * 32 + gg * 8 + e;
      v = (hc < 256) ? invW1[k * 256 + hc] : wembW1[k * 256 + (hc - 256)];
    } else {                               // wembW2 K-slice cgl*128..
      int idx = sub - 4, ct = idx >> 2, ks = idx & 3;
      int col = ct * 128 + r128;
      int k = cgl * 128 + ks * 32 + gg * 8 + e;
      v = wembW2[k * 512 + col];
    }
  }
  Wall[i] = f2bf(v);
}

// ---- fused main kernel: BM=32 acc-resident, 4-deep ring, 56 steps -------
// 32 nodes/block, 512 thr (8 waves), LDS 48KB. Grid 3125 (exact, no guards).
__global__ __launch_bounds__(512, 4) void k_main(
    const float* __restrict__ feats,
    const unsigned short* __restrict__ Wall,
    const unsigned char* __restrict__ act,
    float* __restrict__ out) {
  __shared__ char smem[LDSZ];
  const int tid = threadIdx.x;
  const int lane = tid & 63;
  const int wv = tid >> 6;
  const int o = lane & 15;
  const int g = lane >> 4;
  const int base = blockIdx.x * 32;

  const float inv16 = 0.0625f;
  const float rs32  = 0.17677669529663687f;

  // ---- prologue: S + x loads, convert, stage S; drain before stream ----
  const int srow = tid >> 4, sq = tid & 15;   // 32 rows x 16 slots
  const float* sp = feats + (size_t)(base + srow) * FDIM + sq * 8;
  f32x4 s0 = *(const f32x4*)sp;
  f32x4 s1 = *(const f32x4*)(sp + 4);
  const float* xp = feats + (size_t)(base + srow) * FDIM + 128 + sq * 6;
  f32x2 xa = *(const f32x2*)xp;
  f32x2 xb2 = *(const f32x2*)(xp + 2);
  f32x2 xc = *(const f32x2*)(xp + 4);

  {
    unsigned w0 = cvtpk(s0[0], s0[1]), w1 = cvtpk(s0[2], s0[3]);
    unsigned w2 = cvtpk(s1[0], s1[1]), w3 = cvtpk(s1[2], s1[3]);
    *(u32x4*)(smem + SPO + srow * 256 + ((sq ^ (srow & 15)) << 4)) =
        (u32x4){w0, w1, w2, w3};
  }
  unsigned xr[3];
  xr[0] = cvtpk(xa[0], xa[1]);
  xr[1] = cvtpk(xb2[0], xb2[1]);
  xr[2] = cvtpk(xc[0], xc[1]);
#pragma unroll
  for (int j = 0; j < 3; ++j) KEEP(xr[j]);
  asm volatile("s_waitcnt vmcnt(0)" ::: "memory");
  LGKM_BAR();                              // SPO published

  ISSUE(0); ISSUE(1); ISSUE(2); ISSUE(3);  // ring depth 4

  f32x4 accW[4][2], accA[2], acc2;
#pragma unroll
  for (int ct = 0; ct < 4; ++ct)
#pragma unroll
    for (int rt = 0; rt < 2; ++rt) accW[ct][rt] = (f32x4){0.f, 0.f, 0.f, 0.f};
  accA[0] = (f32x4){0.f, 0.f, 0.f, 0.f};
  accA[1] = (f32x4){0.f, 0.f, 0.f, 0.f};
  acc2 = (f32x4){0.f, 0.f, 0.f, 0.f};

  // ================= 4 col-groups ======================================
#pragma unroll
  for (int cg = 0; cg < 4; ++cg) {
    const int cb = (cg < 2) ? cg * 8 : 16 + (cg - 2) * 20;
    // ---- A: H_cg = silu(S @ W1 panel), 4 chunks -----------------------
#pragma unroll
    for (int ks = 0; ks < 4; ++ks) {
      const int c = cb + ks;
      WAITV_FOR(c);
      __builtin_amdgcn_s_setprio(1);
      bf16x8 b = *(const bf16x8*)(smem + RNG + (c & 3) * 8192 +
                                  (wv * 16 + o) * 64 + ((g ^ (o & 3)) << 4));
#pragma unroll
      for (int rt = 0; rt < 2; ++rt) {
        bf16x8 a = *(const bf16x8*)(smem + SPO + (rt * 16 + o) * 256 +
                                    (((ks * 4 + g) ^ o) << 4));
        accA[rt] = MFMA(a, b, accA[rt]);
      }
      __builtin_amdgcn_s_setprio(0);
      LGKM0();
      ISSUE(c + 4);
    }
    // A epilogue: silu -> HCG (wave's col = wv*16+o)
    {
      const int col = wv * 16 + o;
#pragma unroll
      for (int rt = 0; rt < 2; ++rt) {
#pragma unroll
        for (int rp = 0; rp < 2; ++rp) {
          unsigned w = cvtpk(silu_rs(accA[rt][rp * 2]), silu_rs(accA[rt][rp * 2 + 1]));
          int row0 = rt * 16 + g * 4 + rp * 2;
          *(unsigned short*)(smem + HCG + row0 * 256 +
                             ((col * 2) ^ ((row0 & 15) << 4))) = (unsigned short)w;
          int row1 = row0 + 1;
          *(unsigned short*)(smem + HCG + row1 * 256 +
                             ((col * 2) ^ ((row1 & 15) << 4))) = (unsigned short)(w >> 16);
        }
        accA[rt] = (f32x4){0.f, 0.f, 0.f, 0.f};
      }
    }
    LGKM_BAR();                            // publish H_cg
    // ---- B: contract H_cg against this cg's weight K-slice ------------
    if (cg < 2) {                          // inv: 4 chunks, 1 MFMA each
#pragma unroll
      for (int ks = 0; ks < 4; ++ks) {
        const int c = cb + 4 + ks;
        WAITV_FOR(c);
        __builtin_amdgcn_s_setprio(1);
        bf16x8 b = *(const bf16x8*)(smem + RNG + (c & 3) * 8192 + wv * 1024 +
                                    o * 64 + ((g ^ (o & 3)) << 4));
        bf16x8 a = *(const bf16x8*)(smem + HCG + ((wv & 1) * 16 + o) * 256 +
                                    (((ks * 4 + g) ^ o) << 4));
        acc2 = MFMA(a, b, acc2);
        __builtin_amdgcn_s_setprio(0);
        LGKM0();
        ISSUE(c + 4);
      }
    } else {                               // wemb: 16 chunks (ct x ks)
#pragma unroll
      for (int ct = 0; ct < 4; ++ct)
#pragma unroll
        for (int ks = 0; ks < 4; ++ks) {
          const int c = cb + 4 + ct * 4 + ks;
          WAITV_FOR(c);
          __builtin_amdgcn_s_setprio(1);
          bf16x8 b = *(const bf16x8*)(smem + RNG + (c & 3) * 8192 +
                                      (wv * 16 + o) * 64 + ((g ^ (o & 3)) << 4));
#pragma unroll
          for (int rt = 0; rt < 2; ++rt) {
            bf16x8 a = *(const bf16x8*)(smem + HCG + (rt * 16 + o) * 256 +
                                        (((ks * 4 + g) ^ o) << 4));
            accW[ct][rt] = MFMA(a, b, accW[ct][rt]);
          }
          __builtin_amdgcn_s_setprio(0);
          LGKM0();
          ISSUE(c + 4);
        }
    }
    LGKM_BAR();                            // cg end: H_cg readers done
  }

  // ================= tail: phase C from acc-resident Wm =================
  {
    const int xb = XO + srow * 192 + sq * 12;
    *(unsigned*)(smem + xb + 0) = xr[0];
    *(unsigned*)(smem + xb + 4) = xr[1];
    *(unsigned*)(smem + xb + 8) = xr[2];
  }
  float eq[3] = {0.f, 0.f, 0.f};
  const int nloc = tid >> 4, q = tid & 15;   // 16 thr/node, channel q
#pragma unroll
  for (int Q = 0; Q < 4; ++Q) {
    const int lc = wv * 16 + o;
#pragma unroll
    for (int rt = 0; rt < 2; ++rt)
#pragma unroll
      for (int rp = 0; rp < 2; ++rp) {
        unsigned w = cvtpk(accW[Q][rt][rp * 2] * inv16, accW[Q][rt][rp * 2 + 1] * inv16);
        int n0 = rt * 16 + g * 4 + rp * 2;
        *(unsigned short*)(smem + WMQ + n0 * 256 +
                           ((lc * 2) ^ ((n0 & 15) << 4))) = (unsigned short)w;
        int n1 = n0 + 1;
        *(unsigned short*)(smem + WMQ + n1 * 256 +
                           ((lc * 2) ^ ((n1 & 15) << 4))) = (unsigned short)(w >> 16);
      }
    LGKM_BAR();                            // publish quarter (and XO at Q=0)
#pragma unroll
    for (int il = 0; il < 8; ++il) {
      unsigned short w = *(const unsigned short*)(
          smem + WMQ + nloc * 256 + (((il * 16 + q) * 2) ^ ((nloc & 15) << 4)));
      float wf = bf2f(w);
      const int xb = XO + nloc * 192 + (Q * 24 + il * 3) * 2;
#pragma unroll
      for (int m = 0; m < 3; ++m)
        eq[m] += bf2f(*(const unsigned short*)(smem + xb + m * 2)) * wf;
    }
    if (Q < 3) LGKM_BAR();                 // quarter readers done
  }

  // ---- final stores ----------------------------------------------------
#pragma unroll
  for (int r = 0; r < 4; ++r) {
    int node = base + (wv & 1) * 16 + g * 4 + r;
    float s = act[node] ? inv16 : 0.f;
    out[(size_t)node * OUTC + (wv >> 1) * 16 + o] = acc2[r] * s;
  }
  {
    int node = base + nloc;
    float sC = act[node] ? rs32 : 0.f;
    float* op = out + (size_t)node * OUTC + 64 + q * 3;
    op[0] = eq[0] * sC;
    op[1] = eq[1] * sC;
    op[2] = eq[2] * sC;
  }
}

// ---- launch ------------------------------------------------------------
extern "C" void kernel_launch(void* const* d_in, const int* in_sizes, int n_in,
                              void* d_out, int out_size, void* d_ws, size_t ws_size,
                              hipStream_t stream) {
  const float* feats = (const float*)d_in[0];
  const int* ei = (const int*)d_in[1];
  const float* invW1 = (const float*)d_in[2];
  const float* invW2 = (const float*)d_in[3];
  const float* wembW1 = (const float*)d_in[4];
  const float* wembW2 = (const float*)d_in[5];
  float* out = (float*)d_out;

  char* ws = (char*)d_ws;
  unsigned short* Wall = (unsigned short*)ws;                 // 458752 B
  unsigned char* act = (unsigned char*)(ws + 458752);         // 100096 B

  k_zero<<<98, 256, 0, stream>>>((unsigned int*)act, 25024);
  k_scatter<<<1563, 256, 0, stream>>>(ei, act);
  k_wprep<<<896, 256, 0, stream>>>(invW1, invW2, wembW1, wembW2, Wall);
  k_main<<<3125, 512, 0, stream>>>(feats, Wall, act, out);
}